// Round 2
// baseline (907.267 us; speedup 1.0000x reference)
//
#include <hip/hip_runtime.h>

// NodeModel: edge MLP (Lin->BN->ReLU->Lin) -> scatter_add -> node MLP (same).
// f16 MFMA (16x16x32) with fp32 accumulate; BN stats via two-pass with
// fp32 atomic column sums; h1 recomputed in pass 2 (cheaper than spilling).
// BN first-linear bias is absorbed by BN -> skipped entirely.

typedef _Float16 half8  __attribute__((ext_vector_type(8)));
typedef _Float16 half4h __attribute__((ext_vector_type(4)));
typedef float    floatx4 __attribute__((ext_vector_type(4)));

#define MFMA16(a, b, c) __builtin_amdgcn_mfma_f32_16x16x32_f16(a, b, c, 0, 0, 0)

__device__ __forceinline__ float col_reduce16(float v) {
    // sum over the 4 quads (rows) of a 16x16 MFMA D tile: lanes l, l^16, l^32, l^48
    v += __shfl_xor(v, 16, 64);
    v += __shfl_xor(v, 32, 64);
    return v;
}

// ---------------------------------------------------------------- k_prep ----
// Transpose + f16-convert the four weight matrices into ws.
// w1at[n][k] (128x128), w2at[n][k] (128x128), w1bt[n][k] (128x192), w2bt[n][k] (64x128)
__global__ void k_prep(const float* __restrict__ w1a, const float* __restrict__ w2a,
                       const float* __restrict__ w1b, const float* __restrict__ w2b,
                       _Float16* __restrict__ w1at, _Float16* __restrict__ w2at,
                       _Float16* __restrict__ w1bt, _Float16* __restrict__ w2bt) {
    int i = blockIdx.x * 256 + threadIdx.x;           // 65536 total
    if (i < 16384) {
        int n = i >> 7, k = i & 127;
        w1at[n * 128 + k] = (_Float16)w1a[k * 128 + n];
    } else if (i < 32768) {
        int j = i - 16384; int n = j >> 7, k = j & 127;
        w2at[n * 128 + k] = (_Float16)w2a[k * 128 + n];
    } else if (i < 57344) {
        int j = i - 32768; int n = j / 192, k = j - n * 192;
        w1bt[n * 192 + k] = (_Float16)w1b[k * 128 + n];
    } else if (i < 65536) {
        int j = i - 57344; int n = j >> 7, k = j & 127;
        w2bt[n * 128 + k] = (_Float16)w2b[k * 64 + n];
    }
}

// ---------------------------------------------------------- k_edge_stats ----
// Pass 1 over edges: h1 = concat(x[row], ea) @ W1a ; accumulate col sum/sumsq.
__global__ __launch_bounds__(512, 2) void k_edge_stats(
    const float* __restrict__ x, const int* __restrict__ rowi,
    const float* __restrict__ ea, const _Float16* __restrict__ w1t,
    float* __restrict__ gsum, float* __restrict__ gsq, int E) {
    __shared__ _Float16 sIn[128][136];   // +8 pad: bank-conflict-free b128 frag reads
    __shared__ _Float16 sW[128][136];    // W1^T: [n][k]
    __shared__ float sSum[128], sSq[128];
    const int tid = threadIdx.x, lane = tid & 63, wv = tid >> 6;
    const long e0 = (long)blockIdx.x * 128;

    {   // stage W1^T: 16384 halves, 32 per thread
        int n = tid >> 2, seg = (tid & 3) * 32;
        const half8* src = (const half8*)(w1t + n * 128 + seg);
        half8* dst = (half8*)&sW[n][seg];
        dst[0] = src[0]; dst[1] = src[1]; dst[2] = src[2]; dst[3] = src[3];
    }
    if (tid < 128) { sSum[tid] = 0.f; sSq[tid] = 0.f; }
    {   // stage input tile: cols 0-63 = x[row[e]], 64-127 = edge_attr[e]
        int e = tid >> 2, part = tid & 3;
        long ge = e0 + e;
        bool valid = ge < E;
        const float* src;
        if (part < 2) src = x + (long)(valid ? rowi[ge] : 0) * 64 + part * 32;
        else          src = ea + (long)(valid ? ge : 0) * 64 + (part - 2) * 32;
        _Float16* dst = &sIn[e][part * 32];
#pragma unroll
        for (int i = 0; i < 8; i++) {
            floatx4 v = {0.f, 0.f, 0.f, 0.f};
            if (valid) v = ((const floatx4*)src)[i];
            half4h h = {(_Float16)v[0], (_Float16)v[1], (_Float16)v[2], (_Float16)v[3]};
            *(half4h*)(dst + i * 4) = h;
        }
    }
    __syncthreads();

    const int lm = lane & 15, q = lane >> 4, koff = q * 8;
    half8 a[4];
#pragma unroll
    for (int kb = 0; kb < 4; kb++)
        a[kb] = *(const half8*)&sIn[wv * 16 + lm][kb * 32 + koff];
#pragma unroll
    for (int nt = 0; nt < 8; nt++) {
        floatx4 acc = {0.f, 0.f, 0.f, 0.f};
        const int c = nt * 16 + lm;
#pragma unroll
        for (int kb = 0; kb < 4; kb++) {
            half8 b = *(const half8*)&sW[c][kb * 32 + koff];
            acc = MFMA16(a[kb], b, acc);
        }
        float s  = acc[0] + acc[1] + acc[2] + acc[3];
        float ss = acc[0]*acc[0] + acc[1]*acc[1] + acc[2]*acc[2] + acc[3]*acc[3];
        s = col_reduce16(s); ss = col_reduce16(ss);
        if (q == 0) { atomicAdd(&sSum[c], s); atomicAdd(&sSq[c], ss); }
    }
    __syncthreads();
    if (tid < 128) {
        int slot = blockIdx.x & 15;    // 16-slot spread: cuts same-address contention
        unsafeAtomicAdd(&gsum[slot * 128 + tid], sSum[tid]);
        unsafeAtomicAdd(&gsq[slot * 128 + tid], sSq[tid]);
    }
}

// ------------------------------------------------------------ k_finalize ----
__global__ void k_finalize(const float* __restrict__ sums, const float* __restrict__ sqs,
                           const float* __restrict__ gamma, const float* __restrict__ beta,
                           float* __restrict__ scale, float* __restrict__ shift, float count) {
    int i = threadIdx.x;   // 128
    float s = 0.f, ssq = 0.f;
    for (int j = 0; j < 16; j++) { s += sums[j * 128 + i]; ssq += sqs[j * 128 + i]; }
    float mu = s / count;
    float var = ssq / count - mu * mu;      // biased, matches torch/jax ref
    float sc = gamma[i] * rsqrtf(var + 1e-5f);
    scale[i] = sc;
    shift[i] = beta[i] - mu * sc;
}

// ------------------------------------------------------------ k_edge_mlp ----
// Pass 2: recompute h1, BN+ReLU (in-LDS transpose), GEMM2 (+b2a), scatter_add.
__global__ __launch_bounds__(512, 2) void k_edge_mlp(
    const float* __restrict__ x, const int* __restrict__ rowi, const int* __restrict__ coli,
    const float* __restrict__ ea, const _Float16* __restrict__ w1t, const _Float16* __restrict__ w2t,
    const float* __restrict__ scale, const float* __restrict__ shift, const float* __restrict__ b2a,
    float* __restrict__ agg, int E) {
    __shared__ _Float16 sIn[128][136];   // input tile; reused (transposed) for h_bn
    __shared__ _Float16 sW1[128][136];
    __shared__ _Float16 sW2[128][136];
    __shared__ float sScale[128], sShift[128], sB2[128];
    __shared__ int sColIdx[128];
    const int tid = threadIdx.x, lane = tid & 63, wv = tid >> 6;
    const long e0 = (long)blockIdx.x * 128;

    {   // stage both transposed weight matrices
        int n = tid >> 2, seg = (tid & 3) * 32;
        const half8* s1 = (const half8*)(w1t + n * 128 + seg);
        half8* d1 = (half8*)&sW1[n][seg];
        d1[0] = s1[0]; d1[1] = s1[1]; d1[2] = s1[2]; d1[3] = s1[3];
        const half8* s2 = (const half8*)(w2t + n * 128 + seg);
        half8* d2 = (half8*)&sW2[n][seg];
        d2[0] = s2[0]; d2[1] = s2[1]; d2[2] = s2[2]; d2[3] = s2[3];
    }
    if (tid < 128) {
        sScale[tid] = scale[tid]; sShift[tid] = shift[tid]; sB2[tid] = b2a[tid];
        long ge = e0 + tid;
        sColIdx[tid] = (ge < E) ? coli[ge] : 0;
    }
    {   // stage input tile
        int e = tid >> 2, part = tid & 3;
        long ge = e0 + e;
        bool valid = ge < E;
        const float* src;
        if (part < 2) src = x + (long)(valid ? rowi[ge] : 0) * 64 + part * 32;
        else          src = ea + (long)(valid ? ge : 0) * 64 + (part - 2) * 32;
        _Float16* dst = &sIn[e][part * 32];
#pragma unroll
        for (int i = 0; i < 8; i++) {
            floatx4 v = {0.f, 0.f, 0.f, 0.f};
            if (valid) v = ((const floatx4*)src)[i];
            half4h h = {(_Float16)v[0], (_Float16)v[1], (_Float16)v[2], (_Float16)v[3]};
            *(half4h*)(dst + i * 4) = h;
        }
    }
    __syncthreads();

    const int lm = lane & 15, q = lane >> 4, koff = q * 8;
    // A-fragments into registers: after this (plus barrier) sIn can be reused.
    half8 a[4];
#pragma unroll
    for (int kb = 0; kb < 4; kb++)
        a[kb] = *(const half8*)&sIn[wv * 16 + lm][kb * 32 + koff];

    floatx4 acc1[8];
#pragma unroll
    for (int nt = 0; nt < 8; nt++) {
        floatx4 acc = {0.f, 0.f, 0.f, 0.f};
        const int c = nt * 16 + lm;
#pragma unroll
        for (int kb = 0; kb < 4; kb++) {
            half8 b = *(const half8*)&sW1[c][kb * 32 + koff];
            acc = MFMA16(a[kb], b, acc);
        }
        acc1[nt] = acc;
    }
    __syncthreads();   // all waves done reading sIn (A-frags in regs)

    // BN + ReLU, store h_bn TRANSPOSED: sInT[col][row]; a lane's 4 D-values share
    // a col and have consecutive rows -> one b64 write.
    _Float16(*sInT)[136] = sIn;
#pragma unroll
    for (int nt = 0; nt < 8; nt++) {
        const int c = nt * 16 + lm;
        float sc = sScale[c], sh = sShift[c];
        half4h h;
#pragma unroll
        for (int r = 0; r < 4; r++)
            h[r] = (_Float16)fmaxf(acc1[nt][r] * sc + sh, 0.f);
        *(half4h*)&sInT[c][wv * 16 + q * 4] = h;
    }
    // GEMM2 A-frags read only this wave's own rows (written by this wave).
    // In-wave DS ops complete in order -> no barrier needed.
    half8 a2[4];
#pragma unroll
    for (int kb = 0; kb < 4; kb++) {
#pragma unroll
        for (int j = 0; j < 8; j++)
            a2[kb][j] = sInT[kb * 32 + koff + j][wv * 16 + lm];
    }
#pragma unroll
    for (int nt = 0; nt < 8; nt++) {
        floatx4 acc = {0.f, 0.f, 0.f, 0.f};
        const int c = nt * 16 + lm;
#pragma unroll
        for (int kb = 0; kb < 4; kb++) {
            half8 b = *(const half8*)&sW2[c][kb * 32 + koff];
            acc = MFMA16(a2[kb], b, acc);
        }
        float bb = sB2[c];
#pragma unroll
        for (int r = 0; r < 4; r++) {
            int m = wv * 16 + q * 4 + r;
            long ge = e0 + m;
            if (ge < E)
                unsafeAtomicAdd(&agg[(size_t)sColIdx[m] * 128 + c], acc[r] + bb);
        }
    }
}

// -------------------------------------------------------------- k_node_a ----
// h3 = concat(x, agg) @ W1b  (K=192); store h3 fp32 + BN stats.
__global__ __launch_bounds__(512, 2) void k_node_a(
    const float* __restrict__ x, const float* __restrict__ agg,
    const _Float16* __restrict__ w1bt, float* __restrict__ h3,
    float* __restrict__ gsum, float* __restrict__ gsq, int N) {
    __shared__ _Float16 sIn[128][200];   // 192 + 8 pad
    __shared__ _Float16 sW[128][200];
    __shared__ float sSum[128], sSq[128];
    const int tid = threadIdx.x, lane = tid & 63, wv = tid >> 6;
    const long e0 = (long)blockIdx.x * 128;

    {   // stage W1b^T: each row (192 halves) by 4 threads x 48 halves (6 x half8)
        int n = tid >> 2, seg = (tid & 3) * 48;
        const half8* src = (const half8*)(w1bt + n * 192 + seg);
        half8* dst = (half8*)&sW[n][seg];
        dst[0] = src[0]; dst[1] = src[1]; dst[2] = src[2];
        dst[3] = src[3]; dst[4] = src[4]; dst[5] = src[5];
    }
    if (tid < 128) { sSum[tid] = 0.f; sSq[tid] = 0.f; }
    {
        int m = tid >> 2, seg = tid & 3;
        long gm = e0 + m;
        bool valid = gm < N;
        const float* srcx = x + gm * 64 + seg * 16;
        _Float16* dstx = &sIn[m][seg * 16];
#pragma unroll
        for (int i = 0; i < 4; i++) {
            floatx4 v = {0.f, 0.f, 0.f, 0.f};
            if (valid) v = ((const floatx4*)srcx)[i];
            half4h h = {(_Float16)v[0], (_Float16)v[1], (_Float16)v[2], (_Float16)v[3]};
            *(half4h*)(dstx + i * 4) = h;
        }
        const float* srca = agg + gm * 128 + seg * 32;
        _Float16* dsta = &sIn[m][64 + seg * 32];
#pragma unroll
        for (int i = 0; i < 8; i++) {
            floatx4 v = {0.f, 0.f, 0.f, 0.f};
            if (valid) v = ((const floatx4*)srca)[i];
            half4h h = {(_Float16)v[0], (_Float16)v[1], (_Float16)v[2], (_Float16)v[3]};
            *(half4h*)(dsta + i * 4) = h;
        }
    }
    __syncthreads();

    const int lm = lane & 15, q = lane >> 4, koff = q * 8;
    half8 a[6];
#pragma unroll
    for (int kb = 0; kb < 6; kb++)
        a[kb] = *(const half8*)&sIn[wv * 16 + lm][kb * 32 + koff];
#pragma unroll
    for (int nt = 0; nt < 8; nt++) {
        floatx4 acc = {0.f, 0.f, 0.f, 0.f};
        const int c = nt * 16 + lm;
#pragma unroll
        for (int kb = 0; kb < 6; kb++) {
            half8 b = *(const half8*)&sW[c][kb * 32 + koff];
            acc = MFMA16(a[kb], b, acc);
        }
        float s  = acc[0] + acc[1] + acc[2] + acc[3];
        float ss = acc[0]*acc[0] + acc[1]*acc[1] + acc[2]*acc[2] + acc[3]*acc[3];
        s = col_reduce16(s); ss = col_reduce16(ss);
        if (q == 0) { atomicAdd(&sSum[c], s); atomicAdd(&sSq[c], ss); }
#pragma unroll
        for (int r = 0; r < 4; r++) {
            int m2 = wv * 16 + q * 4 + r;
            long gm2 = e0 + m2;
            if (gm2 < N) h3[gm2 * 128 + c] = acc[r];
        }
    }
    __syncthreads();
    if (tid < 128) {
        int slot = blockIdx.x & 15;
        unsafeAtomicAdd(&gsum[slot * 128 + tid], sSum[tid]);
        unsafeAtomicAdd(&gsq[slot * 128 + tid], sSq[tid]);
    }
}

// -------------------------------------------------------------- k_node_b ----
// out = relu(bn(h3)) @ W2b + b2b  (N-out = 64)
__global__ __launch_bounds__(512, 2) void k_node_b(
    const float* __restrict__ h3, const _Float16* __restrict__ w2bt,
    const float* __restrict__ scale, const float* __restrict__ shift,
    const float* __restrict__ b2b, float* __restrict__ out, int N) {
    __shared__ _Float16 sH[128][136];
    __shared__ _Float16 sW[64][136];
    const int tid = threadIdx.x, lane = tid & 63, wv = tid >> 6;
    const long e0 = (long)blockIdx.x * 128;

    {
        int n = tid >> 3, seg = (tid & 7) * 16;
        const half8* src = (const half8*)(w2bt + n * 128 + seg);
        half8* dst = (half8*)&sW[n][seg];
        dst[0] = src[0]; dst[1] = src[1];
    }
    {   // stage h3 with BN+ReLU applied (invalid rows harmless: outputs guarded)
        int m = tid >> 2, seg = (tid & 3) * 32;
        long gm = e0 + m;
        bool valid = gm < N;
        const float* src = h3 + gm * 128 + seg;
        _Float16* dst = &sH[m][seg];
#pragma unroll
        for (int i = 0; i < 8; i++) {
            floatx4 v = {0.f, 0.f, 0.f, 0.f};
            if (valid) v = ((const floatx4*)src)[i];
            floatx4 sc = ((const floatx4*)(scale + seg))[i];
            floatx4 sh = ((const floatx4*)(shift + seg))[i];
            half4h h;
#pragma unroll
            for (int j = 0; j < 4; j++)
                h[j] = (_Float16)fmaxf(v[j] * sc[j] + sh[j], 0.f);
            *(half4h*)(dst + i * 4) = h;
        }
    }
    __syncthreads();

    const int lm = lane & 15, q = lane >> 4, koff = q * 8;
    half8 a[4];
#pragma unroll
    for (int kb = 0; kb < 4; kb++)
        a[kb] = *(const half8*)&sH[wv * 16 + lm][kb * 32 + koff];
#pragma unroll
    for (int nt = 0; nt < 4; nt++) {
        floatx4 acc = {0.f, 0.f, 0.f, 0.f};
        const int c = nt * 16 + lm;
#pragma unroll
        for (int kb = 0; kb < 4; kb++) {
            half8 b = *(const half8*)&sW[c][kb * 32 + koff];
            acc = MFMA16(a[kb], b, acc);
        }
        float bb = b2b[c];
#pragma unroll
        for (int r = 0; r < 4; r++) {
            int m2 = wv * 16 + q * 4 + r;
            long gm2 = e0 + m2;
            if (gm2 < N) out[gm2 * 64 + c] = acc[r] + bb;
        }
    }
}

// --------------------------------------------------------------- launch -----
extern "C" void kernel_launch(void* const* d_in, const int* in_sizes, int n_in,
                              void* d_out, int out_size, void* d_ws, size_t ws_size,
                              hipStream_t stream) {
    const float* x    = (const float*)d_in[0];
    const int*   eidx = (const int*)d_in[1];
    const float* ea   = (const float*)d_in[2];
    const float* W1a  = (const float*)d_in[5];
    const float* g1a  = (const float*)d_in[7];
    const float* be1a = (const float*)d_in[8];
    const float* W2a  = (const float*)d_in[9];
    const float* b2a  = (const float*)d_in[10];
    const float* W1b  = (const float*)d_in[11];
    const float* g1b  = (const float*)d_in[13];
    const float* be1b = (const float*)d_in[14];
    const float* W2b  = (const float*)d_in[15];
    const float* b2b  = (const float*)d_in[16];
    const int N = in_sizes[0] / 64;
    const int E = in_sizes[2] / 64;
    const int* rowi = eidx;
    const int* coli = eidx + E;

    // workspace layout (floats)
    float* ws   = (float*)d_ws;
    float* agg  = ws;                        // N*128
    float* h3   = ws + (size_t)N * 128;      // N*128
    float* st   = ws + (size_t)N * 256;      // stats block
    float* sumE = st,        * sqE = st + 2048;   // 16 slots x 128
    float* sumN = st + 4096, * sqN = st + 6144;
    float* scE  = st + 8192, * shE = st + 8320;
    float* scN  = st + 8448, * shN = st + 8576;
    _Float16* wh   = (_Float16*)(st + 8704);      // 16B-aligned
    _Float16* w1at = wh;
    _Float16* w2at = wh + 16384;
    _Float16* w1bt = wh + 32768;
    _Float16* w2bt = wh + 57344;

    hipMemsetAsync(agg, 0, (size_t)N * 128 * sizeof(float), stream);
    hipMemsetAsync(st, 0, 8192 * sizeof(float), stream);
    k_prep<<<256, 256, 0, stream>>>(W1a, W2a, W1b, W2b, w1at, w2at, w1bt, w2bt);

    int ebl = (E + 127) / 128;
    int nbl = (N + 127) / 128;
    k_edge_stats<<<ebl, 512, 0, stream>>>(x, rowi, ea, w1at, sumE, sqE, E);
    k_finalize<<<1, 128, 0, stream>>>(sumE, sqE, g1a, be1a, scE, shE, (float)E);
    k_edge_mlp<<<ebl, 512, 0, stream>>>(x, rowi, coli, ea, w1at, w2at, scE, shE, b2a, agg, E);
    k_node_a<<<nbl, 512, 0, stream>>>(x, agg, w1bt, h3, sumN, sqN, N);
    k_finalize<<<1, 128, 0, stream>>>(sumN, sqN, g1b, be1b, scN, shN, (float)N);
    k_node_b<<<nbl, 512, 0, stream>>>(h3, w2bt, scN, shN, b2b, (float*)d_out, N);
}

// Round 3
// 726.893 us; speedup vs baseline: 1.2481x; 1.2481x over previous
//
#include <hip/hip_runtime.h>
#include <hip/hip_fp16.h>

// NodeModel: edge MLP (Lin->BN->ReLU->Lin) -> scatter_add -> node MLP (same).
// f16 MFMA 16x16x32, fp32 accumulate. Two-pass BN (stats then apply+GEMM2).
// R3: multi-tile grid-stride blocks, reg-prefetch pipelining, LDS double
// buffer in edge_mlp, packed-f16 atomics into f16 agg.

typedef _Float16 half8  __attribute__((ext_vector_type(8)));
typedef _Float16 half4h __attribute__((ext_vector_type(4)));
typedef float    floatx4 __attribute__((ext_vector_type(4)));

#define MFMA16(a, b, c) __builtin_amdgcn_mfma_f32_16x16x32_f16(a, b, c, 0, 0, 0)

__device__ __forceinline__ float col_reduce16(float v) {
    v += __shfl_xor(v, 16, 64);
    v += __shfl_xor(v, 32, 64);
    return v;
}

// ---------------------------------------------------------------- k_prep ----
__global__ void k_prep(const float* __restrict__ w1a, const float* __restrict__ w2a,
                       const float* __restrict__ w1b, const float* __restrict__ w2b,
                       _Float16* __restrict__ w1at, _Float16* __restrict__ w2at,
                       _Float16* __restrict__ w1bt, _Float16* __restrict__ w2bt) {
    int i = blockIdx.x * 256 + threadIdx.x;           // 65536 total
    if (i < 16384) {
        int n = i >> 7, k = i & 127;
        w1at[n * 128 + k] = (_Float16)w1a[k * 128 + n];
    } else if (i < 32768) {
        int j = i - 16384; int n = j >> 7, k = j & 127;
        w2at[n * 128 + k] = (_Float16)w2a[k * 128 + n];
    } else if (i < 57344) {
        int j = i - 32768; int n = j / 192, k = j - n * 192;
        w1bt[n * 192 + k] = (_Float16)w1b[k * 128 + n];
    } else if (i < 65536) {
        int j = i - 57344; int n = j >> 7, k = j & 127;
        w2bt[n * 128 + k] = (_Float16)w2b[k * 64 + n];
    }
}

// ---------------------------------------------------------- k_edge_stats ----
// Pass 1: h1 = concat(x[row],ea) @ W1a; per-lane reg accumulation of col
// sum/sumsq; one global atomic per col per block at the end.
// LDS ~70 KB -> 2 blocks/CU. Reg-prefetch of next tile overlaps GEMM1.
__global__ __launch_bounds__(512, 4) void k_edge_stats(
    const float* __restrict__ x, const int* __restrict__ rowi,
    const float* __restrict__ ea, const _Float16* __restrict__ w1t,
    float* __restrict__ gsum, float* __restrict__ gsq, int nTiles) {
    __shared__ _Float16 sW[128][136];
    __shared__ _Float16 sIn[128][136];
    const int tid = threadIdx.x, lane = tid & 63, wv = tid >> 6;
    const int lm = lane & 15, q = lane >> 4, koff = q * 8;
    const int G = gridDim.x;
    const int e = tid >> 2, part = tid & 3;

    {   // stage W1^T once
        int n = tid >> 2, seg = (tid & 3) * 32;
        const half8* src = (const half8*)(w1t + n * 128 + seg);
        half8* dst = (half8*)&sW[n][seg];
        dst[0] = src[0]; dst[1] = src[1]; dst[2] = src[2]; dst[3] = src[3];
    }
    float sAcc[8], ssAcc[8];
#pragma unroll
    for (int i = 0; i < 8; i++) { sAcc[i] = 0.f; ssAcc[i] = 0.f; }

    int t = blockIdx.x;
    floatx4 pv[8];
    {   // prologue load of tile t
        long ge = (long)t * 128 + e;
        const float* src = (part < 2) ? x + (long)rowi[ge] * 64 + part * 32
                                      : ea + ge * 64 + (part - 2) * 32;
#pragma unroll
        for (int i = 0; i < 8; i++) pv[i] = ((const floatx4*)src)[i];
    }
    for (; t < nTiles; t += G) {
        {   // regs -> LDS (convert f32->f16)
            _Float16* dst = &sIn[e][part * 32];
#pragma unroll
            for (int i = 0; i < 8; i++) {
                half4h h = {(_Float16)pv[i][0], (_Float16)pv[i][1],
                            (_Float16)pv[i][2], (_Float16)pv[i][3]};
                *(half4h*)(dst + i * 4) = h;
            }
        }
        __syncthreads();
        int tn = t + G;
        if (tn < nTiles) {   // prefetch next tile into regs (overlaps GEMM1)
            long ge = (long)tn * 128 + e;
            const float* src = (part < 2) ? x + (long)rowi[ge] * 64 + part * 32
                                          : ea + ge * 64 + (part - 2) * 32;
#pragma unroll
            for (int i = 0; i < 8; i++) pv[i] = ((const floatx4*)src)[i];
        }
        half8 a[4];
#pragma unroll
        for (int kb = 0; kb < 4; kb++)
            a[kb] = *(const half8*)&sIn[wv * 16 + lm][kb * 32 + koff];
#pragma unroll
        for (int nt = 0; nt < 8; nt++) {
            floatx4 acc = {0.f, 0.f, 0.f, 0.f};
            const int c = nt * 16 + lm;
#pragma unroll
            for (int kb = 0; kb < 4; kb++) {
                half8 b = *(const half8*)&sW[c][kb * 32 + koff];
                acc = MFMA16(a[kb], b, acc);
            }
            sAcc[nt]  += acc[0] + acc[1] + acc[2] + acc[3];
            ssAcc[nt] += acc[0]*acc[0] + acc[1]*acc[1] + acc[2]*acc[2] + acc[3]*acc[3];
        }
        __syncthreads();
    }
#pragma unroll
    for (int nt = 0; nt < 8; nt++) {
        float s  = col_reduce16(sAcc[nt]);
        float ss = col_reduce16(ssAcc[nt]);
        if (q == 0) {
            int c = nt * 16 + lm;
            int slot = (blockIdx.x * 8 + wv) & 15;
            unsafeAtomicAdd(&gsum[slot * 128 + c], s);
            unsafeAtomicAdd(&gsq[slot * 128 + c], ss);
        }
    }
}

// ------------------------------------------------------------ k_finalize ----
__global__ void k_finalize(const float* __restrict__ sums, const float* __restrict__ sqs,
                           const float* __restrict__ gamma, const float* __restrict__ beta,
                           float* __restrict__ scale, float* __restrict__ shift, float count) {
    int i = threadIdx.x;   // 128
    float s = 0.f, ssq = 0.f;
    for (int j = 0; j < 16; j++) { s += sums[j * 128 + i]; ssq += sqs[j * 128 + i]; }
    float mu = s / count;
    float var = ssq / count - mu * mu;      // biased, matches torch/jax ref
    float sc = gamma[i] * rsqrtf(var + 1e-5f);
    scale[i] = sc;
    shift[i] = beta[i] - mu * sc;
}

// ------------------------------------------------------------ k_edge_mlp ----
// Pass 2: recompute h1, BN+ReLU (in-LDS transpose), GEMM2(+b2a), pk-f16
// atomic scatter into f16 agg. LDS double buffer; grid-stride tiles.
__global__ __launch_bounds__(512, 2) void k_edge_mlp(
    const float* __restrict__ x, const int* __restrict__ rowi, const int* __restrict__ coli,
    const float* __restrict__ ea, const _Float16* __restrict__ w1t, const _Float16* __restrict__ w2t,
    const float* __restrict__ scale, const float* __restrict__ shift, const float* __restrict__ b2a,
    __half* __restrict__ agg, int nTiles) {
    __shared__ _Float16 sW1[128][136];
    __shared__ _Float16 sW2[128][136];
    __shared__ _Float16 sIn[2][128][136];   // input tile / h_bn transpose scratch
    __shared__ float sScale[128], sShift[128], sB2[128];
    __shared__ int sCol[2][128];
    const int tid = threadIdx.x, lane = tid & 63, wv = tid >> 6;
    const int lm = lane & 15, q = lane >> 4, koff = q * 8;
    const int G = gridDim.x;
    const int e = tid >> 2, part = tid & 3;

    {   // stage both weight matrices once
        int n = tid >> 2, seg = (tid & 3) * 32;
        const half8* s1 = (const half8*)(w1t + n * 128 + seg);
        half8* d1 = (half8*)&sW1[n][seg];
        d1[0] = s1[0]; d1[1] = s1[1]; d1[2] = s1[2]; d1[3] = s1[3];
        const half8* s2 = (const half8*)(w2t + n * 128 + seg);
        half8* d2 = (half8*)&sW2[n][seg];
        d2[0] = s2[0]; d2[1] = s2[1]; d2[2] = s2[2]; d2[3] = s2[3];
    }
    if (tid < 128) { sScale[tid] = scale[tid]; sShift[tid] = shift[tid]; sB2[tid] = b2a[tid]; }

    int t = blockIdx.x;
    {   // prologue: stage tile t into buf 0
        long ge = (long)t * 128 + e;
        const float* src = (part < 2) ? x + (long)rowi[ge] * 64 + part * 32
                                      : ea + ge * 64 + (part - 2) * 32;
        _Float16* dst = &sIn[0][e][part * 32];
#pragma unroll
        for (int i = 0; i < 8; i++) {
            floatx4 v = ((const floatx4*)src)[i];
            half4h h = {(_Float16)v[0], (_Float16)v[1], (_Float16)v[2], (_Float16)v[3]};
            *(half4h*)(dst + i * 4) = h;
        }
        if (tid < 128) sCol[0][tid] = coli[(long)t * 128 + tid];
    }
    __syncthreads();
    int p = 0;
    for (; t < nTiles; t += G) {
        half8 a[4];
#pragma unroll
        for (int kb = 0; kb < 4; kb++)
            a[kb] = *(const half8*)&sIn[p][wv * 16 + lm][kb * 32 + koff];
        int myCol[4];
#pragma unroll
        for (int r = 0; r < 4; r++) myCol[r] = sCol[p][wv * 16 + q * 4 + r];

        int tn = t + G; bool hasNext = tn < nTiles;
        floatx4 pv[8]; int pcol = 0;
        if (hasNext) {   // prefetch next tile into regs (overlaps both GEMMs)
            long ge = (long)tn * 128 + e;
            const float* src = (part < 2) ? x + (long)rowi[ge] * 64 + part * 32
                                          : ea + ge * 64 + (part - 2) * 32;
#pragma unroll
            for (int i = 0; i < 8; i++) pv[i] = ((const floatx4*)src)[i];
            if (tid < 128) pcol = coli[(long)tn * 128 + tid];
        }
        // GEMM1
        floatx4 acc1[8];
#pragma unroll
        for (int nt = 0; nt < 8; nt++) {
            floatx4 acc = {0.f, 0.f, 0.f, 0.f};
            const int c = nt * 16 + lm;
#pragma unroll
            for (int kb = 0; kb < 4; kb++) {
                half8 b = *(const half8*)&sW1[c][kb * 32 + koff];
                acc = MFMA16(a[kb], b, acc);
            }
            acc1[nt] = acc;
        }
        __syncthreads();   // all waves done reading sIn[p]

        // BN+ReLU, write h_bn transposed into sIn[p]
        _Float16(*sT)[136] = sIn[p];
#pragma unroll
        for (int nt = 0; nt < 8; nt++) {
            const int c = nt * 16 + lm;
            float sc = sScale[c], sh = sShift[c];
            half4h h;
#pragma unroll
            for (int r = 0; r < 4; r++)
                h[r] = (_Float16)fmaxf(acc1[nt][r] * sc + sh, 0.f);
            *(half4h*)&sT[c][wv * 16 + q * 4] = h;
        }
        // own-wave rows only -> no barrier (in-wave DS ordering)
        half8 a2[4];
#pragma unroll
        for (int kb = 0; kb < 4; kb++) {
#pragma unroll
            for (int j = 0; j < 8; j++)
                a2[kb][j] = sT[kb * 32 + koff + j][wv * 16 + lm];
        }
        // GEMM2
#pragma unroll
        for (int nt = 0; nt < 8; nt++) {
            floatx4 acc = {0.f, 0.f, 0.f, 0.f};
            const int c = nt * 16 + lm;
#pragma unroll
            for (int kb = 0; kb < 4; kb++) {
                half8 b = *(const half8*)&sW2[c][kb * 32 + koff];
                acc = MFMA16(a2[kb], b, acc);
            }
            acc1[nt] = acc;   // reuse regs
        }
        // store prefetched tile into the other buffer
        if (hasNext) {
            _Float16* dst = &sIn[p ^ 1][e][part * 32];
#pragma unroll
            for (int i = 0; i < 8; i++) {
                half4h h = {(_Float16)pv[i][0], (_Float16)pv[i][1],
                            (_Float16)pv[i][2], (_Float16)pv[i][3]};
                *(half4h*)(dst + i * 4) = h;
            }
            if (tid < 128) sCol[p ^ 1][tid] = pcol;
        }
        // packed-f16 atomic scatter: lanes lm,lm^1 pair adjacent cols
#pragma unroll
        for (int nt = 0; nt < 8; nt++) {
            const int c = nt * 16 + lm;
            const int c0 = c & ~1;
            float bb = sB2[c];
            float v0 = acc1[nt][0] + bb, v1 = acc1[nt][1] + bb;
            float v2 = acc1[nt][2] + bb, v3 = acc1[nt][3] + bb;
            float p0 = __shfl_xor(v0, 1, 64), p1 = __shfl_xor(v1, 1, 64);
            float p2 = __shfl_xor(v2, 1, 64), p3 = __shfl_xor(v3, 1, 64);
            if ((lane & 1) == 0) {
                unsafeAtomicAdd((__half2*)&agg[(size_t)myCol[0] * 128 + c0], __floats2half2_rn(v0, p0));
                unsafeAtomicAdd((__half2*)&agg[(size_t)myCol[1] * 128 + c0], __floats2half2_rn(v1, p1));
            } else {
                unsafeAtomicAdd((__half2*)&agg[(size_t)myCol[2] * 128 + c0], __floats2half2_rn(p2, v2));
                unsafeAtomicAdd((__half2*)&agg[(size_t)myCol[3] * 128 + c0], __floats2half2_rn(p3, v3));
            }
        }
        __syncthreads();   // buf p^1 staged + visible for next iter
        p ^= 1;
    }
}

// -------------------------------------------------------------- k_node_a ----
// h3 = concat(x, agg_f16) @ W1b (K=192); store h3 fp32 + BN stats.
__global__ __launch_bounds__(512, 2) void k_node_a(
    const float* __restrict__ x, const __half* __restrict__ agg,
    const _Float16* __restrict__ w1bt, float* __restrict__ h3,
    float* __restrict__ gsum, float* __restrict__ gsq, int N) {
    __shared__ _Float16 sIn[128][200];   // 192 + 8 pad
    __shared__ _Float16 sW[128][200];
    __shared__ float sSum[128], sSq[128];
    const int tid = threadIdx.x, lane = tid & 63, wv = tid >> 6;
    const long e0 = (long)blockIdx.x * 128;

    {   // stage W1b^T: each row 192 halves by 4 threads x 48 halves
        int n = tid >> 2, seg = (tid & 3) * 48;
        const half8* src = (const half8*)(w1bt + n * 192 + seg);
        half8* dst = (half8*)&sW[n][seg];
        dst[0] = src[0]; dst[1] = src[1]; dst[2] = src[2];
        dst[3] = src[3]; dst[4] = src[4]; dst[5] = src[5];
    }
    if (tid < 128) { sSum[tid] = 0.f; sSq[tid] = 0.f; }
    {
        int m = tid >> 2, seg = tid & 3;
        long gm = e0 + m;
        bool valid = gm < N;
        const float* srcx = x + gm * 64 + seg * 16;
        _Float16* dstx = &sIn[m][seg * 16];
#pragma unroll
        for (int i = 0; i < 4; i++) {
            floatx4 v = {0.f, 0.f, 0.f, 0.f};
            if (valid) v = ((const floatx4*)srcx)[i];
            half4h h = {(_Float16)v[0], (_Float16)v[1], (_Float16)v[2], (_Float16)v[3]};
            *(half4h*)(dstx + i * 4) = h;
        }
        const _Float16* srca = (const _Float16*)agg + gm * 128 + seg * 32;
        _Float16* dsta = &sIn[m][64 + seg * 32];
#pragma unroll
        for (int i = 0; i < 4; i++) {
            half8 v = {0, 0, 0, 0, 0, 0, 0, 0};
            if (valid) v = ((const half8*)srca)[i];
            *(half8*)(dsta + i * 8) = v;
        }
    }
    __syncthreads();

    const int lm = lane & 15, q = lane >> 4, koff = q * 8;
    half8 a[6];
#pragma unroll
    for (int kb = 0; kb < 6; kb++)
        a[kb] = *(const half8*)&sIn[wv * 16 + lm][kb * 32 + koff];
#pragma unroll
    for (int nt = 0; nt < 8; nt++) {
        floatx4 acc = {0.f, 0.f, 0.f, 0.f};
        const int c = nt * 16 + lm;
#pragma unroll
        for (int kb = 0; kb < 6; kb++) {
            half8 b = *(const half8*)&sW[c][kb * 32 + koff];
            acc = MFMA16(a[kb], b, acc);
        }
        float s  = acc[0] + acc[1] + acc[2] + acc[3];
        float ss = acc[0]*acc[0] + acc[1]*acc[1] + acc[2]*acc[2] + acc[3]*acc[3];
        s = col_reduce16(s); ss = col_reduce16(ss);
        if (q == 0) { atomicAdd(&sSum[c], s); atomicAdd(&sSq[c], ss); }
#pragma unroll
        for (int r = 0; r < 4; r++) {
            int m2 = wv * 16 + q * 4 + r;
            long gm2 = e0 + m2;
            if (gm2 < N) h3[gm2 * 128 + c] = acc[r];
        }
    }
    __syncthreads();
    if (tid < 128) {
        int slot = blockIdx.x & 15;
        unsafeAtomicAdd(&gsum[slot * 128 + tid], sSum[tid]);
        unsafeAtomicAdd(&gsq[slot * 128 + tid], sSq[tid]);
    }
}

// -------------------------------------------------------------- k_node_b ----
__global__ __launch_bounds__(512, 2) void k_node_b(
    const float* __restrict__ h3, const _Float16* __restrict__ w2bt,
    const float* __restrict__ scale, const float* __restrict__ shift,
    const float* __restrict__ b2b, float* __restrict__ out, int N) {
    __shared__ _Float16 sH[128][136];
    __shared__ _Float16 sW[64][136];
    const int tid = threadIdx.x, lane = tid & 63, wv = tid >> 6;
    const long e0 = (long)blockIdx.x * 128;

    {
        int n = tid >> 3, seg = (tid & 7) * 16;
        const half8* src = (const half8*)(w2bt + n * 128 + seg);
        half8* dst = (half8*)&sW[n][seg];
        dst[0] = src[0]; dst[1] = src[1];
    }
    {   // stage h3 with BN+ReLU applied
        int m = tid >> 2, seg = (tid & 3) * 32;
        long gm = e0 + m;
        bool valid = gm < N;
        const float* src = h3 + gm * 128 + seg;
        _Float16* dst = &sH[m][seg];
#pragma unroll
        for (int i = 0; i < 8; i++) {
            floatx4 v = {0.f, 0.f, 0.f, 0.f};
            if (valid) v = ((const floatx4*)src)[i];
            floatx4 sc = ((const floatx4*)(scale + seg))[i];
            floatx4 sh = ((const floatx4*)(shift + seg))[i];
            half4h h;
#pragma unroll
            for (int j = 0; j < 4; j++)
                h[j] = (_Float16)fmaxf(v[j] * sc[j] + sh[j], 0.f);
            *(half4h*)(dst + i * 4) = h;
        }
    }
    __syncthreads();

    const int lm = lane & 15, q = lane >> 4, koff = q * 8;
    half8 a[4];
#pragma unroll
    for (int kb = 0; kb < 4; kb++)
        a[kb] = *(const half8*)&sH[wv * 16 + lm][kb * 32 + koff];
#pragma unroll
    for (int nt = 0; nt < 4; nt++) {
        floatx4 acc = {0.f, 0.f, 0.f, 0.f};
        const int c = nt * 16 + lm;
#pragma unroll
        for (int kb = 0; kb < 4; kb++) {
            half8 b = *(const half8*)&sW[c][kb * 32 + koff];
            acc = MFMA16(a[kb], b, acc);
        }
        float bb = b2b[c];
#pragma unroll
        for (int r = 0; r < 4; r++) {
            int m2 = wv * 16 + q * 4 + r;
            long gm2 = e0 + m2;
            if (gm2 < N) out[gm2 * 64 + c] = acc[r] + bb;
        }
    }
}

// --------------------------------------------------------------- launch -----
extern "C" void kernel_launch(void* const* d_in, const int* in_sizes, int n_in,
                              void* d_out, int out_size, void* d_ws, size_t ws_size,
                              hipStream_t stream) {
    const float* x    = (const float*)d_in[0];
    const int*   eidx = (const int*)d_in[1];
    const float* ea   = (const float*)d_in[2];
    const float* W1a  = (const float*)d_in[5];
    const float* g1a  = (const float*)d_in[7];
    const float* be1a = (const float*)d_in[8];
    const float* W2a  = (const float*)d_in[9];
    const float* b2a  = (const float*)d_in[10];
    const float* W1b  = (const float*)d_in[11];
    const float* g1b  = (const float*)d_in[13];
    const float* be1b = (const float*)d_in[14];
    const float* W2b  = (const float*)d_in[15];
    const float* b2b  = (const float*)d_in[16];
    const int N = in_sizes[0] / 64;
    const int E = in_sizes[2] / 64;
    const int* rowi = eidx;
    const int* coli = eidx + E;

    // workspace layout
    float* ws   = (float*)d_ws;
    __half* agg = (__half*)ws;                    // N*128 halves (= N*64 floats)
    float* h3   = ws + (size_t)N * 64;            // N*128 floats
    float* st   = h3 + (size_t)N * 128;           // stats block
    float* sumE = st,        * sqE = st + 2048;   // 16 slots x 128
    float* sumN = st + 4096, * sqN = st + 6144;
    float* scE  = st + 8192, * shE = st + 8320;
    float* scN  = st + 8448, * shN = st + 8576;
    _Float16* wh   = (_Float16*)(st + 8704);      // 16B-aligned
    _Float16* w1at = wh;
    _Float16* w2at = wh + 16384;
    _Float16* w1bt = wh + 32768;
    _Float16* w2bt = wh + 57344;

    hipMemsetAsync(agg, 0, (size_t)N * 128 * sizeof(__half), stream);
    hipMemsetAsync(st, 0, 8192 * sizeof(float), stream);
    k_prep<<<256, 256, 0, stream>>>(W1a, W2a, W1b, W2b, w1at, w2at, w1bt, w2bt);

    int nTilesE = E / 128;                        // E = 800000 -> 6250 exact
    int nbl = (N + 127) / 128;
    k_edge_stats<<<500, 512, 0, stream>>>(x, rowi, ea, w1at, sumE, sqE, nTilesE);
    k_finalize<<<1, 128, 0, stream>>>(sumE, sqE, g1a, be1a, scE, shE, (float)E);
    k_edge_mlp<<<250, 512, 0, stream>>>(x, rowi, coli, ea, w1at, w2at, scE, shE, b2a, agg, nTilesE);
    k_node_a<<<nbl, 512, 0, stream>>>(x, agg, w1bt, h3, sumN, sqN, N);
    k_finalize<<<1, 128, 0, stream>>>(sumN, sqN, g1b, be1b, scN, shN, (float)N);
    k_node_b<<<nbl, 512, 0, stream>>>(h3, w2bt, scN, shN, b2b, (float*)d_out, N);
}